// Round 5
// baseline (188.241 us; speedup 1.0000x reference)
//
#include <hip/hip_runtime.h>

typedef short bf16x8 __attribute__((ext_vector_type(8)));
typedef float f32x16 __attribute__((ext_vector_type(16)));

#define DI __device__ __forceinline__

constexpr int BS = 2, CH = 128;
constexpr int NQ = 16384, NM = 4096;
constexpr size_t NX = (size_t)BS * CH * NQ;   // elements per output tensor

DI float bf2f(ushort u) { unsigned v = ((unsigned)u) << 16; return __builtin_bit_cast(float, v); }
DI ushort f2bf(float f) {
  unsigned u = __builtin_bit_cast(unsigned, f);
  u += 0x7FFFu + ((u >> 16) & 1u);   // RNE
  return (ushort)(u >> 16);
}
DI float ldany(const void* p, size_t i, int f) {
  return f ? ((const float*)p)[i] : bf2f(((const ushort*)p)[i]);
}
DI f32x16 mfma_bf16(bf16x8 a, bf16x8 b, f32x16 c) {
  return __builtin_amdgcn_mfma_f32_32x32x16_bf16(a, b, c, 0, 0, 0);
}

// ---------------- dtype sniff ----------------
__global__ void k_sniff(const void* __restrict__ x, int* __restrict__ flag) {
  if (threadIdx.x == 0 && blockIdx.x == 0) {
    const ushort* u = (const ushort*)x;
    int garbage = 0, zeros = 0;
    for (int i = 0; i < 256; ++i) {
      float v = bf2f(u[i]);
      if (!(fabsf(v) < 1e9f)) garbage++;
      if ((i & 1) == 0 && u[i] == 0) zeros++;
    }
    flag[0] = (garbage >= 8 || zeros >= 100) ? 1 : 0;   // 1 = f32 buffers
  }
}

// ---------------- weight prep ----------------
__global__ __launch_bounds__(256) void k_prep(
    const void* __restrict__ wT, const void* __restrict__ bT,
    const void* __restrict__ wP, const void* __restrict__ bP,
    const void* __restrict__ wG, const void* __restrict__ bG,
    const void* __restrict__ wAG, const void* __restrict__ bAG,
    const int* __restrict__ flag,
    float* __restrict__ wAllf, float* __restrict__ bAllf, uint4* __restrict__ wF)
{
  int t = threadIdx.x;
  int f = flag[0];
  if (blockIdx.x == 0) {
    for (int i = t; i < 16 * 128; i += 256) wAllf[i]        = ldany(wT, i, f);
    for (int i = t; i < 16 * 128; i += 256) wAllf[2048 + i] = ldany(wP, i, f);
    for (int i = t; i < 64 * 128; i += 256) wAllf[4096 + i] = ldany(wG, i, f);
    if (t < 16)  bAllf[t]       = ldany(bT, t, f);
    if (t < 16)  bAllf[16 + t]  = ldany(bP, t, f);
    if (t < 64)  bAllf[32 + t]  = ldany(bG, t, f);
    if (t < 128) bAllf[96 + t]  = ldany(bAG, t, f);
  } else {
    int idx = (blockIdx.x - 1) * 256 + t;  // 0..1023
    int lane = idx & 63, ks = (idx >> 6) & 3, ot = idx >> 8;
    size_t src = (size_t)(ot * 32 + (lane & 31)) * 64 + ks * 16 + (lane >> 5) * 8;
    union { uint4 v4; ushort s[8]; } o;
    #pragma unroll
    for (int j = 0; j < 8; ++j) o.s[j] = f2bf(ldany(wAG, src + j, f));
    wF[idx] = o.v4;
  }
}

// ---------------- projections ----------------
// grp 0-1: theta (tanh * log2e, bf16 [q][16])
// grp 2-3: phi   (maxpool pre-act, tanh, bf16 [m][16])
// grp 4-11: g    (maxpool, bf16 transposed g_t[c][m])
__global__ __launch_bounds__(256) void k_proj(
    const void* __restrict__ x, const int* __restrict__ flag,
    const float* __restrict__ wAllf, const float* __restrict__ bAllf,
    ushort* __restrict__ theta, ushort* __restrict__ phi, ushort* __restrict__ g_t)
{
  int b = blockIdx.y;
  int grp = blockIdx.x >> 5, qt = blockIdx.x & 31;
  int t = threadIdx.x, lane = t & 63, wv = t >> 6;
  int q = qt * 512 + wv * 128 + lane * 2;
  int f = flag[0];
  const float* wp = wAllf + (grp << 10);

  float a0[8], a1[8];
  #pragma unroll
  for (int o = 0; o < 8; ++o) { a0[o] = 0.f; a1[o] = 0.f; }

  size_t xoff = (size_t)b * CH * NQ + q;
  if (f) {
    const float* xf = (const float*)x + xoff;
    for (int c0 = 0; c0 < CH; c0 += 8) {
      float2 xv[8];
      #pragma unroll
      for (int k = 0; k < 8; ++k) xv[k] = *(const float2*)(xf + (size_t)(c0 + k) * NQ);
      #pragma unroll
      for (int o = 0; o < 8; ++o) {
        #pragma unroll
        for (int k = 0; k < 8; ++k) {
          float wgt = wp[o * 128 + c0 + k];
          a0[o] = fmaf(xv[k].x, wgt, a0[o]);
          a1[o] = fmaf(xv[k].y, wgt, a1[o]);
        }
      }
    }
  } else {
    const ushort* xu = (const ushort*)x + xoff;
    for (int c0 = 0; c0 < CH; c0 += 8) {
      float xl[8], xh[8];
      #pragma unroll
      for (int k = 0; k < 8; ++k) {
        uint v = *(const uint*)(xu + (size_t)(c0 + k) * NQ);
        xl[k] = bf2f((ushort)(v & 0xFFFFu));
        xh[k] = bf2f((ushort)(v >> 16));
      }
      #pragma unroll
      for (int o = 0; o < 8; ++o) {
        #pragma unroll
        for (int k = 0; k < 8; ++k) {
          float wgt = wp[o * 128 + c0 + k];
          a0[o] = fmaf(xl[k], wgt, a0[o]);
          a1[o] = fmaf(xh[k], wgt, a1[o]);
        }
      }
    }
  }

  int bb = grp * 8;
  constexpr float L2E = 1.4426950408889634f;

  if (grp < 2) {
    union { uint4 v4; ushort s[8]; } t0, t1;
    #pragma unroll
    for (int o = 0; o < 8; ++o) {
      t0.s[o] = f2bf(tanhf(a0[o] + bAllf[bb + o]) * L2E);
      t1.s[o] = f2bf(tanhf(a1[o] + bAllf[bb + o]) * L2E);
    }
    *(uint4*)(theta + ((size_t)b * NQ + q) * 16 + bb)     = t0.v4;
    *(uint4*)(theta + ((size_t)b * NQ + q + 1) * 16 + bb) = t1.v4;
  } else {
    float z[8];
    #pragma unroll
    for (int o = 0; o < 8; ++o) {
      float m2 = fmaxf(a0[o], a1[o]) + bAllf[bb + o];   // h-pair in-thread
      z[o] = fmaxf(m2, __shfl_xor(m2, 16, 64));          // w-pair across lanes
    }
    if ((lane & 16) == 0) {
      int hh = q & 31, ww = (q >> 5) & 31, nn = q >> 10;
      int m = nn * 256 + (ww >> 1) * 16 + (hh >> 1);
      if (grp < 4) {
        union { uint4 v4; ushort s[8]; } ph;
        #pragma unroll
        for (int o = 0; o < 8; ++o) ph.s[o] = f2bf(tanhf(z[o]));
        *(uint4*)(phi + ((size_t)b * NM + m) * 16 + (bb - 16)) = ph.v4;
      } else {
        int c0 = bb - 32;
        #pragma unroll
        for (int o = 0; o < 8; ++o)
          g_t[((size_t)b * 64 + c0 + o) * NM + m] = f2bf(z[o]);
      }
    }
  }
}

// ---------------- softmax denominator partials ----------------
// 32-way deterministic q-split, 8 blocks/CU.
__global__ __launch_bounds__(256, 8) void k_denom(
    const ushort* __restrict__ theta, const ushort* __restrict__ phi,
    float* __restrict__ partial)
{
  int b = blockIdx.z, qs = blockIdx.y;
  int w = threadIdx.x >> 6;
  int l = threadIdx.x & 63, lr = l & 31, lh = l >> 5;
  int m0 = blockIdx.x * 128 + w * 32;

  bf16x8 pB = __builtin_bit_cast(bf16x8, *(const uint4*)(phi + ((size_t)b * NM + m0 + lr) * 16 + lh * 8));

  float s = 0.f;
  int qb = qs * 512;
  for (int qq = 0; qq < 512; qq += 32) {
    bf16x8 tA = __builtin_bit_cast(bf16x8, *(const uint4*)(theta + ((size_t)b * NQ + qb + qq + lr) * 16 + lh * 8));
    f32x16 S;
    #pragma unroll
    for (int i = 0; i < 16; ++i) S[i] = 0.f;
    S = mfma_bf16(tA, pB, S);
    #pragma unroll
    for (int r = 0; r < 16; ++r) s += exp2f(S[r]);
  }
  s += __shfl_xor(s, 32, 64);
  if (l < 32) partial[(((size_t)b * 32 + qs) << 12) + m0 + lr] = s;
}

// ---------------- denominator reduce -> dinv ----------------
__global__ __launch_bounds__(256) void k_dinv(
    const float* __restrict__ partial, float* __restrict__ dinv)
{
  int idx = blockIdx.x * 256 + threadIdx.x;   // 8192
  int b = idx >> 12, m = idx & 4095;
  float s = 0.f;
  #pragma unroll
  for (int p = 0; p < 32; ++p) s += partial[(((size_t)b * 32 + p) << 12) + m];
  dinv[idx] = 1.f / s;
}

// ---------------- fold 1/denom into g_t (in place; k_proj rewrites each call) --
__global__ __launch_bounds__(256) void k_gs(
    const float* __restrict__ dinv, ushort* __restrict__ g_t)
{
  size_t base = ((size_t)blockIdx.x * 256 + threadIdx.x) * 8;  // over 2*64*4096
  int m = (int)(base & 4095);
  int b = (int)(base >> 18);
  union { uint4 v4; ushort s[8]; } v;
  v.v4 = *(uint4*)(g_t + base);
  const float* dp = dinv + b * 4096 + m;
  #pragma unroll
  for (int j = 0; j < 8; ++j) v.s[j] = f2bf(bf2f(v.s[j]) * dp[j]);
  *(uint4*)(g_t + base) = v.v4;
}

// ---------------- fused attention + output ----------------
// 1024 threads = 16 waves = (qh 2) x (mq 8). 64 q per block; wave loop: 16 iters
// over m (m0 = mq*32 + it*256). Swapped QK^T (S^T[m][q]); P = exp2(S) unnormalized
// (scale folded into gs); PV A-frags in-register via cvt_pk + permlane32_swap.
// Grid 512 blocks = 2 blocks/CU = 32 waves/CU.
__global__ __launch_bounds__(1024, 8) void k_attn(
    const ushort* __restrict__ theta, const ushort* __restrict__ phi,
    const ushort* __restrict__ gs_t, const uint4* __restrict__ wF,
    const float* __restrict__ bAllf, const void* __restrict__ x,
    const void* __restrict__ gamma, const int* __restrict__ flag,
    void* __restrict__ out_base)
{
  int b = blockIdx.y;
  int q0 = blockIdx.x * 64;
  int t = threadIdx.x;
  int w = t >> 6, l = t & 63, lr = l & 31, lh = l >> 5;
  int mq = w & 7, qh = w >> 3;

  __shared__ float agPart[8][32][65];
  __shared__ __align__(16) ushort agF[32][80];

  int qw = q0 + qh * 32;
  bf16x8 tB = __builtin_bit_cast(bf16x8, *(const uint4*)(theta + ((size_t)b * NQ + qw + lr) * 16 + lh * 8));

  const ushort* gt0 = gs_t + ((size_t)b * 64 + lr) * NM;
  const ushort* gt1 = gt0 + (size_t)32 * NM;

  f32x16 acc0, acc1;
  #pragma unroll
  for (int i = 0; i < 16; ++i) { acc0[i] = 0.f; acc1[i] = 0.f; }

  for (int it = 0; it < 16; ++it) {
    int m0 = mq * 32 + it * 256;
    bf16x8 pA = __builtin_bit_cast(bf16x8, *(const uint4*)(phi + ((size_t)b * NM + m0 + lr) * 16 + lh * 8));

    f32x16 S;
    #pragma unroll
    for (int i = 0; i < 16; ++i) S[i] = 0.f;
    S = mfma_bf16(pA, tB, S);   // S^T[m][q] (theta pre-scaled by log2e)

    uint4 g00 = *(const uint4*)(gt0 + m0 + lh * 8);
    uint4 g01 = *(const uint4*)(gt1 + m0 + lh * 8);
    uint4 g10 = *(const uint4*)(gt0 + m0 + 16 + lh * 8);
    uint4 g11 = *(const uint4*)(gt1 + m0 + 16 + lh * 8);

    #pragma unroll
    for (int r = 0; r < 16; ++r) S[r] = exp2f(S[r]);   // unnormalized P

    uint u0, u1, u2, u3, u4, u5, u6, u7;
    asm("v_cvt_pk_bf16_f32 %0, %1, %2" : "=v"(u0) : "v"(S[0]),  "v"(S[1]));
    asm("v_cvt_pk_bf16_f32 %0, %1, %2" : "=v"(u1) : "v"(S[2]),  "v"(S[3]));
    asm("v_cvt_pk_bf16_f32 %0, %1, %2" : "=v"(u2) : "v"(S[4]),  "v"(S[5]));
    asm("v_cvt_pk_bf16_f32 %0, %1, %2" : "=v"(u3) : "v"(S[6]),  "v"(S[7]));
    asm("v_cvt_pk_bf16_f32 %0, %1, %2" : "=v"(u4) : "v"(S[8]),  "v"(S[9]));
    asm("v_cvt_pk_bf16_f32 %0, %1, %2" : "=v"(u5) : "v"(S[10]), "v"(S[11]));
    asm("v_cvt_pk_bf16_f32 %0, %1, %2" : "=v"(u6) : "v"(S[12]), "v"(S[13]));
    asm("v_cvt_pk_bf16_f32 %0, %1, %2" : "=v"(u7) : "v"(S[14]), "v"(S[15]));

    asm("v_permlane32_swap_b32 %0, %1" : "+v"(u0), "+v"(u2));
    asm("v_permlane32_swap_b32 %0, %1" : "+v"(u1), "+v"(u3));
    asm("v_permlane32_swap_b32 %0, %1" : "+v"(u4), "+v"(u6));
    asm("v_permlane32_swap_b32 %0, %1" : "+v"(u5), "+v"(u7));

    uint4 fa0 = make_uint4(u0, u1, u2, u3);
    uint4 fa1 = make_uint4(u4, u5, u6, u7);

    acc0 = mfma_bf16(__builtin_bit_cast(bf16x8, fa0), __builtin_bit_cast(bf16x8, g00), acc0);
    acc1 = mfma_bf16(__builtin_bit_cast(bf16x8, fa0), __builtin_bit_cast(bf16x8, g01), acc1);
    acc0 = mfma_bf16(__builtin_bit_cast(bf16x8, fa1), __builtin_bit_cast(bf16x8, g10), acc0);
    acc1 = mfma_bf16(__builtin_bit_cast(bf16x8, fa1), __builtin_bit_cast(bf16x8, g11), acc1);
  }

  int mode = flag[0];
  float ga = ldany(gamma, 0, mode);
  float alpha = 1.f / (1.f + __expf(-ga));

  #pragma unroll
  for (int h = 0; h < 2; ++h) {
    __syncthreads();
    if (qh == h) {
      #pragma unroll
      for (int r = 0; r < 16; ++r) {
        int qq = (r & 3) + 8 * (r >> 2) + 4 * lh;
        agPart[mq][qq][lr]      = acc0[r];
        agPart[mq][qq][32 + lr] = acc1[r];
      }
    }
    __syncthreads();
    if (t < 256) {
      int w2 = t >> 6, l2 = t & 63, lr2 = l2 & 31, lh2 = l2 >> 5;
      #pragma unroll
      for (int jj = 0; jj < 8; ++jj) {
        int c = w2 * 16 + lh2 * 8 + jj;
        float vsum = 0.f;
        #pragma unroll
        for (int p = 0; p < 8; ++p) vsum += agPart[p][lr2][c];
        agF[lr2][c] = f2bf(vsum);
      }
    }
    __syncthreads();
    if (qh == h && mq < 4) {
      f32x16 oacc;
      #pragma unroll
      for (int i = 0; i < 16; ++i) oacc[i] = 0.f;
      #pragma unroll
      for (int ks = 0; ks < 4; ++ks) {
        bf16x8 aw = __builtin_bit_cast(bf16x8, wF[(mq * 4 + ks) * 64 + l]);
        bf16x8 bg = __builtin_bit_cast(bf16x8, *(const uint4*)&agF[lr][ks * 16 + lh * 8]);
        oacc = mfma_bf16(aw, bg, oacc);
      }
      if (mode) {
        float* o0 = (float*)out_base;
        float* o1 = o0 + NX;
        const float* xf = (const float*)x;
        #pragma unroll
        for (int r = 0; r < 16; ++r) {
          int o = mq * 32 + (r & 3) + 8 * (r >> 2) + 4 * lh;
          size_t oi = ((size_t)b * CH + o) * NQ + q0 + h * 32 + lr;
          float ag = oacc[r] + bAllf[96 + o];
          o0[oi] = (1.f - alpha) * xf[oi] + alpha * ag;
          o1[oi] = ag;
        }
      } else {
        ushort* o0 = (ushort*)out_base;
        ushort* o1 = o0 + NX;
        const ushort* xu = (const ushort*)x;
        #pragma unroll
        for (int r = 0; r < 16; ++r) {
          int o = mq * 32 + (r & 3) + 8 * (r >> 2) + 4 * lh;
          size_t oi = ((size_t)b * CH + o) * NQ + q0 + h * 32 + lr;
          float ag = oacc[r] + bAllf[96 + o];
          o0[oi] = f2bf((1.f - alpha) * bf2f(xu[oi]) + alpha * ag);
          o1[oi] = f2bf(ag);
        }
      }
    }
  }
}

extern "C" void kernel_launch(void* const* d_in, const int* in_sizes, int n_in,
                              void* d_out, int out_size, void* d_ws, size_t ws_size,
                              hipStream_t stream) {
  const void* x    = d_in[0];
  const void* wT   = d_in[1];
  const void* bT   = d_in[2];
  const void* wP   = d_in[3];
  const void* bP   = d_in[4];
  const void* wG   = d_in[5];
  const void* bG   = d_in[6];
  const void* wAG  = d_in[7];
  const void* bAG  = d_in[8];
  const void* gmm  = d_in[9];

  char* ws = (char*)d_ws;
  ushort* theta  = (ushort*)(ws + 0);          // 1 MB
  ushort* phi    = (ushort*)(ws + 1048576);    // 256 KB
  ushort* g_t    = (ushort*)(ws + 1310720);    // 1 MB  [b][c][m] bf16
  float*  part   = (float*) (ws + 2359296);    // 1 MB
  float*  dinv   = (float*) (ws + 3407872);    // 32 KB
  uint4*  wF     = (uint4*) (ws + 3440640);    // 16 KB
  float*  wAllf  = (float*) (ws + 3457024);    // 48 KB
  float*  bAllf  = (float*) (ws + 3506176);    // 1 KB
  int*    flag   = (int*)   (ws + 3507200);    // 4 B

  k_sniff<<<dim3(1), dim3(64), 0, stream>>>(x, flag);
  k_prep<<<dim3(5), dim3(256), 0, stream>>>(wT, bT, wP, bP, wG, bG, wAG, bAG, flag, wAllf, bAllf, wF);
  k_proj<<<dim3(384, 2), dim3(256), 0, stream>>>(x, flag, wAllf, bAllf, theta, phi, g_t);
  k_denom<<<dim3(32, 32, 2), dim3(256), 0, stream>>>(theta, phi, part);
  k_dinv<<<dim3(32), dim3(256), 0, stream>>>(part, dinv);
  k_gs<<<dim3(256), dim3(256), 0, stream>>>(dinv, g_t);
  k_attn<<<dim3(256, 2), dim3(1024), 0, stream>>>(theta, phi, g_t, wF, bAllf, x, gmm, flag, d_out);
}

// Round 6
// 184.404 us; speedup vs baseline: 1.0208x; 1.0208x over previous
//
#include <hip/hip_runtime.h>

typedef short bf16x8 __attribute__((ext_vector_type(8)));
typedef float f32x16 __attribute__((ext_vector_type(16)));

#define DI __device__ __forceinline__

constexpr int BS = 2, CH = 128;
constexpr int NQ = 16384, NM = 4096;
constexpr size_t NX = (size_t)BS * CH * NQ;   // elements per output tensor

DI float bf2f(ushort u) { unsigned v = ((unsigned)u) << 16; return __builtin_bit_cast(float, v); }
DI ushort f2bf(float f) {
  unsigned u = __builtin_bit_cast(unsigned, f);
  u += 0x7FFFu + ((u >> 16) & 1u);   // RNE
  return (ushort)(u >> 16);
}
DI float ldany(const void* p, size_t i, int f) {
  return f ? ((const float*)p)[i] : bf2f(((const ushort*)p)[i]);
}
DI f32x16 mfma_bf16(bf16x8 a, bf16x8 b, f32x16 c) {
  return __builtin_amdgcn_mfma_f32_32x32x16_bf16(a, b, c, 0, 0, 0);
}

// ---------------- dtype sniff ----------------
__global__ void k_sniff(const void* __restrict__ x, int* __restrict__ flag) {
  if (threadIdx.x == 0 && blockIdx.x == 0) {
    const ushort* u = (const ushort*)x;
    int garbage = 0, zeros = 0;
    for (int i = 0; i < 256; ++i) {
      float v = bf2f(u[i]);
      if (!(fabsf(v) < 1e9f)) garbage++;
      if ((i & 1) == 0 && u[i] == 0) zeros++;
    }
    flag[0] = (garbage >= 8 || zeros >= 100) ? 1 : 0;   // 1 = f32 buffers
  }
}

// ---------------- canonicalize x to bf16 (f32 mode only) ----------------
__global__ __launch_bounds__(256) void k_convert(
    const void* __restrict__ x, const int* __restrict__ flag, ushort* __restrict__ xc)
{
  if (!flag[0]) return;
  size_t i = ((size_t)blockIdx.x * 256 + threadIdx.x) * 8;
  const float* xf = (const float*)x;
  union { uint4 v4; ushort s[8]; } o;
  #pragma unroll
  for (int k = 0; k < 8; ++k) o.s[k] = f2bf(xf[i + k]);
  *(uint4*)(xc + i) = o.v4;
}

// ---------------- weight prep ----------------
__global__ __launch_bounds__(256) void k_prep(
    const void* __restrict__ wT, const void* __restrict__ bT,
    const void* __restrict__ wP, const void* __restrict__ bP,
    const void* __restrict__ wG, const void* __restrict__ bG,
    const void* __restrict__ wAG, const void* __restrict__ bAG,
    const int* __restrict__ flag,
    float* __restrict__ wAllf, float* __restrict__ bAllf, uint4* __restrict__ wF)
{
  int t = threadIdx.x;
  int f = flag[0];
  if (blockIdx.x == 0) {
    for (int i = t; i < 16 * 128; i += 256) wAllf[i]        = ldany(wT, i, f);
    for (int i = t; i < 16 * 128; i += 256) wAllf[2048 + i] = ldany(wP, i, f);
    for (int i = t; i < 64 * 128; i += 256) wAllf[4096 + i] = ldany(wG, i, f);
    if (t < 16)  bAllf[t]       = ldany(bT, t, f);
    if (t < 16)  bAllf[16 + t]  = ldany(bP, t, f);
    if (t < 64)  bAllf[32 + t]  = ldany(bG, t, f);
    if (t < 128) bAllf[96 + t]  = ldany(bAG, t, f);
  } else {
    int idx = (blockIdx.x - 1) * 256 + t;  // 0..1023
    int lane = idx & 63, ks = (idx >> 6) & 3, ot = idx >> 8;
    size_t src = (size_t)(ot * 32 + (lane & 31)) * 64 + ks * 16 + (lane >> 5) * 8;
    union { uint4 v4; ushort s[8]; } o;
    #pragma unroll
    for (int j = 0; j < 8; ++j) o.s[j] = f2bf(ldany(wAG, src + j, f));
    wF[idx] = o.v4;
  }
}

// ---------------- projections ----------------
// 6 channel-groups of 16 outputs, 1 q per thread, bf16 x (xc in f32 mode).
// grp 0: theta (tanh * log2e) | grp 1: phi (pool, tanh) | grp 2-5: g (pool, g_t[c][m])
__global__ __launch_bounds__(256) void k_proj(
    const void* __restrict__ x, const ushort* __restrict__ xc,
    const int* __restrict__ flag,
    const float* __restrict__ wAllf, const float* __restrict__ bAllf,
    ushort* __restrict__ theta, ushort* __restrict__ phi, ushort* __restrict__ g_t)
{
  int b = blockIdx.y;
  int grp = blockIdx.x >> 6, qt = blockIdx.x & 63;
  int t = threadIdx.x, lane = t & 63;
  int q = qt * 256 + t;
  int f = flag[0];
  const float* wp = wAllf + (grp << 11);

  const ushort* xb = (f ? xc : (const ushort*)x) + (size_t)b * CH * NQ + q;

  float acc[16];
  #pragma unroll
  for (int o = 0; o < 16; ++o) acc[o] = 0.f;

  for (int c0 = 0; c0 < CH; c0 += 8) {
    float xv[8];
    #pragma unroll
    for (int k = 0; k < 8; ++k) xv[k] = bf2f(xb[(size_t)(c0 + k) * NQ]);
    #pragma unroll
    for (int o = 0; o < 16; ++o) {
      #pragma unroll
      for (int k = 0; k < 8; ++k) acc[o] = fmaf(xv[k], wp[o * 128 + c0 + k], acc[o]);
    }
  }

  int bb = grp * 16;
  constexpr float L2E = 1.4426950408889634f;

  if (grp == 0) {
    union { uint4 v4[2]; ushort s[16]; } th;
    #pragma unroll
    for (int o = 0; o < 16; ++o) th.s[o] = f2bf(tanhf(acc[o] + bAllf[o]) * L2E);
    uint4* dst = (uint4*)(theta + ((size_t)b * NQ + q) * 16);
    dst[0] = th.v4[0]; dst[1] = th.v4[1];
  } else {
    float z[16];
    #pragma unroll
    for (int o = 0; o < 16; ++o) {
      float m2 = acc[o] + bAllf[bb + o];
      m2 = fmaxf(m2, __shfl_xor(m2, 1, 64));    // h-pair
      z[o] = fmaxf(m2, __shfl_xor(m2, 32, 64)); // w-pair
    }
    if ((lane & 1) == 0 && (lane & 32) == 0) {
      int hh = q & 31, ww = (q >> 5) & 31, nn = q >> 10;
      int m = nn * 256 + (ww >> 1) * 16 + (hh >> 1);
      if (grp == 1) {
        union { uint4 v4[2]; ushort s[16]; } ph;
        #pragma unroll
        for (int o = 0; o < 16; ++o) ph.s[o] = f2bf(tanhf(z[o]));
        uint4* pdst = (uint4*)(phi + ((size_t)b * NM + m) * 16);
        pdst[0] = ph.v4[0]; pdst[1] = ph.v4[1];
      } else {
        int c0 = bb - 32;
        #pragma unroll
        for (int o = 0; o < 16; ++o)
          g_t[((size_t)b * 64 + c0 + o) * NM + m] = f2bf(z[o]);
      }
    }
  }
}

// ---------------- softmax denominator partials ----------------
__global__ __launch_bounds__(256, 8) void k_denom(
    const ushort* __restrict__ theta, const ushort* __restrict__ phi,
    float* __restrict__ partial)
{
  int b = blockIdx.z, qs = blockIdx.y;
  int w = threadIdx.x >> 6;
  int l = threadIdx.x & 63, lr = l & 31, lh = l >> 5;
  int m0 = blockIdx.x * 128 + w * 32;

  bf16x8 pB = __builtin_bit_cast(bf16x8, *(const uint4*)(phi + ((size_t)b * NM + m0 + lr) * 16 + lh * 8));

  float s = 0.f;
  int qb = qs * 512;
  for (int qq = 0; qq < 512; qq += 32) {
    bf16x8 tA = __builtin_bit_cast(bf16x8, *(const uint4*)(theta + ((size_t)b * NQ + qb + qq + lr) * 16 + lh * 8));
    f32x16 S;
    #pragma unroll
    for (int i = 0; i < 16; ++i) S[i] = 0.f;
    S = mfma_bf16(tA, pB, S);
    #pragma unroll
    for (int r = 0; r < 16; ++r) s += exp2f(S[r]);
  }
  s += __shfl_xor(s, 32, 64);
  if (l < 32) partial[(((size_t)b * 32 + qs) << 12) + m0 + lr] = s;
}

// ---------------- denominator reduce -> dinv ----------------
__global__ __launch_bounds__(256) void k_dinv(
    const float* __restrict__ partial, float* __restrict__ dinv)
{
  int idx = blockIdx.x * 256 + threadIdx.x;   // 8192
  int b = idx >> 12, m = idx & 4095;
  float s = 0.f;
  #pragma unroll
  for (int p = 0; p < 32; ++p) s += partial[(((size_t)b * 32 + p) << 12) + m];
  dinv[idx] = 1.f / s;
}

// ---------------- fold 1/denom into g_t ----------------
__global__ __launch_bounds__(256) void k_gs(
    const float* __restrict__ dinv, ushort* __restrict__ g_t)
{
  size_t base = ((size_t)blockIdx.x * 256 + threadIdx.x) * 8;  // over 2*64*4096
  int m = (int)(base & 4095);
  int b = (int)(base >> 18);
  union { uint4 v4; ushort s[8]; } v;
  v.v4 = *(uint4*)(g_t + base);
  const float* dp = dinv + b * 4096 + m;
  #pragma unroll
  for (int j = 0; j < 8; ++j) v.s[j] = f2bf(bf2f(v.s[j]) * dp[j]);
  *(uint4*)(g_t + base) = v.v4;
}

// ---------------- fused attention + output ----------------
// 1024 threads = 16 waves = (qh 2) x (mq 8); 64 q/block; 16 m-iters/wave.
// launch_bounds(1024,4) -> 128-VGPR cap (R5's (1024,8) forced 32 VGPR = spills).
// 1-deep prefetch of pA/g frags hides L2 latency under exp/pack/PV.
__global__ __launch_bounds__(1024, 4) void k_attn(
    const ushort* __restrict__ theta, const ushort* __restrict__ phi,
    const ushort* __restrict__ gs_t, const uint4* __restrict__ wF,
    const float* __restrict__ bAllf, const void* __restrict__ x,
    const void* __restrict__ gamma, const int* __restrict__ flag,
    void* __restrict__ out_base)
{
  int b = blockIdx.y;
  int q0 = blockIdx.x * 64;
  int t = threadIdx.x;
  int w = t >> 6, l = t & 63, lr = l & 31, lh = l >> 5;
  int mq = w & 7, qh = w >> 3;

  __shared__ float agPart[8][32][65];
  __shared__ __align__(16) ushort agF[32][80];

  int qw = q0 + qh * 32;
  bf16x8 tB = __builtin_bit_cast(bf16x8, *(const uint4*)(theta + ((size_t)b * NQ + qw + lr) * 16 + lh * 8));

  const ushort* phb = phi + ((size_t)b * NM + lr) * 16 + lh * 8;
  const ushort* gt0 = gs_t + ((size_t)b * 64 + lr) * NM;
  const ushort* gt1 = gt0 + (size_t)32 * NM;

  f32x16 acc0, acc1;
  #pragma unroll
  for (int i = 0; i < 16; ++i) { acc0[i] = 0.f; acc1[i] = 0.f; }

  int m0 = mq * 32;
  bf16x8 pA = __builtin_bit_cast(bf16x8, *(const uint4*)(phb + (size_t)m0 * 16));
  uint4 g00 = *(const uint4*)(gt0 + m0 + lh * 8);
  uint4 g01 = *(const uint4*)(gt1 + m0 + lh * 8);
  uint4 g10 = *(const uint4*)(gt0 + m0 + 16 + lh * 8);
  uint4 g11 = *(const uint4*)(gt1 + m0 + 16 + lh * 8);

  for (int it = 0; it < 16; ++it) {
    f32x16 S;
    #pragma unroll
    for (int i = 0; i < 16; ++i) S[i] = 0.f;
    S = mfma_bf16(pA, tB, S);   // S^T[m][q] (theta pre-scaled by log2e)

    int mn = mq * 32 + ((it + 1) & 15) * 256;   // next-iter frags (wrap: unused)
    bf16x8 pAn = __builtin_bit_cast(bf16x8, *(const uint4*)(phb + (size_t)mn * 16));
    uint4 n00 = *(const uint4*)(gt0 + mn + lh * 8);
    uint4 n01 = *(const uint4*)(gt1 + mn + lh * 8);
    uint4 n10 = *(const uint4*)(gt0 + mn + 16 + lh * 8);
    uint4 n11 = *(const uint4*)(gt1 + mn + 16 + lh * 8);

    #pragma unroll
    for (int r = 0; r < 16; ++r) S[r] = exp2f(S[r]);   // unnormalized P

    uint u0, u1, u2, u3, u4, u5, u6, u7;
    asm("v_cvt_pk_bf16_f32 %0, %1, %2" : "=v"(u0) : "v"(S[0]),  "v"(S[1]));
    asm("v_cvt_pk_bf16_f32 %0, %1, %2" : "=v"(u1) : "v"(S[2]),  "v"(S[3]));
    asm("v_cvt_pk_bf16_f32 %0, %1, %2" : "=v"(u2) : "v"(S[4]),  "v"(S[5]));
    asm("v_cvt_pk_bf16_f32 %0, %1, %2" : "=v"(u3) : "v"(S[6]),  "v"(S[7]));
    asm("v_cvt_pk_bf16_f32 %0, %1, %2" : "=v"(u4) : "v"(S[8]),  "v"(S[9]));
    asm("v_cvt_pk_bf16_f32 %0, %1, %2" : "=v"(u5) : "v"(S[10]), "v"(S[11]));
    asm("v_cvt_pk_bf16_f32 %0, %1, %2" : "=v"(u6) : "v"(S[12]), "v"(S[13]));
    asm("v_cvt_pk_bf16_f32 %0, %1, %2" : "=v"(u7) : "v"(S[14]), "v"(S[15]));

    asm("v_permlane32_swap_b32 %0, %1" : "+v"(u0), "+v"(u2));
    asm("v_permlane32_swap_b32 %0, %1" : "+v"(u1), "+v"(u3));
    asm("v_permlane32_swap_b32 %0, %1" : "+v"(u4), "+v"(u6));
    asm("v_permlane32_swap_b32 %0, %1" : "+v"(u5), "+v"(u7));

    uint4 fa0 = make_uint4(u0, u1, u2, u3);
    uint4 fa1 = make_uint4(u4, u5, u6, u7);

    acc0 = mfma_bf16(__builtin_bit_cast(bf16x8, fa0), __builtin_bit_cast(bf16x8, g00), acc0);
    acc1 = mfma_bf16(__builtin_bit_cast(bf16x8, fa0), __builtin_bit_cast(bf16x8, g01), acc1);
    acc0 = mfma_bf16(__builtin_bit_cast(bf16x8, fa1), __builtin_bit_cast(bf16x8, g10), acc0);
    acc1 = mfma_bf16(__builtin_bit_cast(bf16x8, fa1), __builtin_bit_cast(bf16x8, g11), acc1);

    pA = pAn; g00 = n00; g01 = n01; g10 = n10; g11 = n11;
  }

  int mode = flag[0];
  float ga = ldany(gamma, 0, mode);
  float alpha = 1.f / (1.f + __expf(-ga));

  #pragma unroll
  for (int h = 0; h < 2; ++h) {
    __syncthreads();
    if (qh == h) {
      #pragma unroll
      for (int r = 0; r < 16; ++r) {
        int qq = (r & 3) + 8 * (r >> 2) + 4 * lh;
        agPart[mq][qq][lr]      = acc0[r];
        agPart[mq][qq][32 + lr] = acc1[r];
      }
    }
    __syncthreads();
    if (t < 256) {
      int w2 = t >> 6, l2 = t & 63, lr2 = l2 & 31, lh2 = l2 >> 5;
      #pragma unroll
      for (int jj = 0; jj < 8; ++jj) {
        int c = w2 * 16 + lh2 * 8 + jj;
        float vsum = 0.f;
        #pragma unroll
        for (int p = 0; p < 8; ++p) vsum += agPart[p][lr2][c];
        agF[lr2][c] = f2bf(vsum);
      }
    }
    __syncthreads();
    if (qh == h && mq < 4) {
      f32x16 oacc;
      #pragma unroll
      for (int i = 0; i < 16; ++i) oacc[i] = 0.f;
      #pragma unroll
      for (int ks = 0; ks < 4; ++ks) {
        bf16x8 aw = __builtin_bit_cast(bf16x8, wF[(mq * 4 + ks) * 64 + l]);
        bf16x8 bg = __builtin_bit_cast(bf16x8, *(const uint4*)&agF[lr][ks * 16 + lh * 8]);
        oacc = mfma_bf16(aw, bg, oacc);
      }
      if (mode) {
        float* o0 = (float*)out_base;
        float* o1 = o0 + NX;
        const float* xf = (const float*)x;
        #pragma unroll
        for (int r = 0; r < 16; ++r) {
          int o = mq * 32 + (r & 3) + 8 * (r >> 2) + 4 * lh;
          size_t oi = ((size_t)b * CH + o) * NQ + q0 + h * 32 + lr;
          float ag = oacc[r] + bAllf[96 + o];
          o0[oi] = (1.f - alpha) * xf[oi] + alpha * ag;
          o1[oi] = ag;
        }
      } else {
        ushort* o0 = (ushort*)out_base;
        ushort* o1 = o0 + NX;
        const ushort* xu = (const ushort*)x;
        #pragma unroll
        for (int r = 0; r < 16; ++r) {
          int o = mq * 32 + (r & 3) + 8 * (r >> 2) + 4 * lh;
          size_t oi = ((size_t)b * CH + o) * NQ + q0 + h * 32 + lr;
          float ag = oacc[r] + bAllf[96 + o];
          o0[oi] = f2bf((1.f - alpha) * bf2f(xu[oi]) + alpha * ag);
          o1[oi] = f2bf(ag);
        }
      }
    }
  }
}

extern "C" void kernel_launch(void* const* d_in, const int* in_sizes, int n_in,
                              void* d_out, int out_size, void* d_ws, size_t ws_size,
                              hipStream_t stream) {
  const void* x    = d_in[0];
  const void* wT   = d_in[1];
  const void* bT   = d_in[2];
  const void* wP   = d_in[3];
  const void* bP   = d_in[4];
  const void* wG   = d_in[5];
  const void* bG   = d_in[6];
  const void* wAG  = d_in[7];
  const void* bAG  = d_in[8];
  const void* gmm  = d_in[9];

  char* ws = (char*)d_ws;
  ushort* theta  = (ushort*)(ws + 0);          // 1 MB
  ushort* phi    = (ushort*)(ws + 1048576);    // 256 KB
  ushort* g_t    = (ushort*)(ws + 1310720);    // 1 MB  [b][c][m] bf16
  float*  part   = (float*) (ws + 2359296);    // 1 MB
  float*  dinv   = (float*) (ws + 3407872);    // 32 KB
  uint4*  wF     = (uint4*) (ws + 3440640);    // 16 KB
  float*  wAllf  = (float*) (ws + 3457024);    // 48 KB
  float*  bAllf  = (float*) (ws + 3506176);    // 1 KB
  int*    flag   = (int*)   (ws + 3507200);    // 4 B
  ushort* xc     = (ushort*)(ws + 3507456);    // 8 MB canonical bf16 x

  k_sniff<<<dim3(1), dim3(64), 0, stream>>>(x, flag);
  k_convert<<<dim3(2048), dim3(256), 0, stream>>>(x, flag, xc);
  k_prep<<<dim3(5), dim3(256), 0, stream>>>(wT, bT, wP, bP, wG, bG, wAG, bAG, flag, wAllf, bAllf, wF);
  k_proj<<<dim3(384, 2), dim3(256), 0, stream>>>(x, xc, flag, wAllf, bAllf, theta, phi, g_t);
  k_denom<<<dim3(32, 32, 2), dim3(256), 0, stream>>>(theta, phi, part);
  k_dinv<<<dim3(32), dim3(256), 0, stream>>>(part, dinv);
  k_gs<<<dim3(256), dim3(256), 0, stream>>>(dinv, g_t);
  k_attn<<<dim3(256, 2), dim3(1024), 0, stream>>>(theta, phi, g_t, wF, bAllf, x, gmm, flag, d_out);
}

// Round 7
// 158.788 us; speedup vs baseline: 1.1855x; 1.1613x over previous
//
#include <hip/hip_runtime.h>

typedef short bf16x8 __attribute__((ext_vector_type(8)));
typedef float f32x16 __attribute__((ext_vector_type(16)));

#define DI __device__ __forceinline__

constexpr int BS = 2, CH = 128;
constexpr int NQ = 16384, NM = 4096;
constexpr size_t NX = (size_t)BS * CH * NQ;   // elements per output tensor

DI float bf2f(ushort u) { unsigned v = ((unsigned)u) << 16; return __builtin_bit_cast(float, v); }
DI ushort f2bf(float f) {
  unsigned u = __builtin_bit_cast(unsigned, f);
  u += 0x7FFFu + ((u >> 16) & 1u);   // RNE
  return (ushort)(u >> 16);
}
DI float ldany(const void* p, size_t i, int f) {
  return f ? ((const float*)p)[i] : bf2f(((const ushort*)p)[i]);
}
DI f32x16 mfma_bf16(bf16x8 a, bf16x8 b, f32x16 c) {
  return __builtin_amdgcn_mfma_f32_32x32x16_bf16(a, b, c, 0, 0, 0);
}

// ---------------- dtype sniff ----------------
__global__ void k_sniff(const void* __restrict__ x, int* __restrict__ flag) {
  if (threadIdx.x == 0 && blockIdx.x == 0) {
    const ushort* u = (const ushort*)x;
    int garbage = 0, zeros = 0;
    for (int i = 0; i < 256; ++i) {
      float v = bf2f(u[i]);
      if (!(fabsf(v) < 1e9f)) garbage++;
      if ((i & 1) == 0 && u[i] == 0) zeros++;
    }
    flag[0] = (garbage >= 8 || zeros >= 100) ? 1 : 0;   // 1 = f32 buffers
  }
}

// ---------------- canonicalize x to bf16 (f32 mode only) ----------------
__global__ __launch_bounds__(256) void k_convert(
    const void* __restrict__ x, const int* __restrict__ flag, ushort* __restrict__ xc)
{
  if (!flag[0]) return;
  size_t i = ((size_t)blockIdx.x * 256 + threadIdx.x) * 8;
  const float* xf = (const float*)x;
  union { uint4 v4; ushort s[8]; } o;
  #pragma unroll
  for (int k = 0; k < 8; ++k) o.s[k] = f2bf(xf[i + k]);
  *(uint4*)(xc + i) = o.v4;
}

// ---------------- weight prep ----------------
__global__ __launch_bounds__(256) void k_prep(
    const void* __restrict__ wT, const void* __restrict__ bT,
    const void* __restrict__ wP, const void* __restrict__ bP,
    const void* __restrict__ wG, const void* __restrict__ bG,
    const void* __restrict__ wAG, const void* __restrict__ bAG,
    const int* __restrict__ flag,
    float* __restrict__ wAllf, float* __restrict__ bAllf, uint4* __restrict__ wF)
{
  int t = threadIdx.x;
  int f = flag[0];
  if (blockIdx.x == 0) {
    for (int i = t; i < 16 * 128; i += 256) wAllf[i]        = ldany(wT, i, f);
    for (int i = t; i < 16 * 128; i += 256) wAllf[2048 + i] = ldany(wP, i, f);
    for (int i = t; i < 64 * 128; i += 256) wAllf[4096 + i] = ldany(wG, i, f);
    if (t < 16)  bAllf[t]       = ldany(bT, t, f);
    if (t < 16)  bAllf[16 + t]  = ldany(bP, t, f);
    if (t < 64)  bAllf[32 + t]  = ldany(bG, t, f);
    if (t < 128) bAllf[96 + t]  = ldany(bAG, t, f);
  } else {
    int idx = (blockIdx.x - 1) * 256 + t;  // 0..1023
    int lane = idx & 63, ks = (idx >> 6) & 3, ot = idx >> 8;
    size_t src = (size_t)(ot * 32 + (lane & 31)) * 64 + ks * 16 + (lane >> 5) * 8;
    union { uint4 v4; ushort s[8]; } o;
    #pragma unroll
    for (int j = 0; j < 8; ++j) o.s[j] = f2bf(ldany(wAG, src + j, f));
    wF[idx] = o.v4;
  }
}

// ---------------- projections ----------------
// 6 channel-groups of 16 outputs, 1 q per thread, bf16 x (xc in f32 mode).
// grp 0: theta (tanh * log2e) | grp 1: phi (pool, tanh) | grp 2-5: g (pool,
// row-major gm[m][64] bf16 -- coalesced 32B stores; frag-pack happens in k_gsf)
__global__ __launch_bounds__(256) void k_proj(
    const void* __restrict__ x, const ushort* __restrict__ xc,
    const int* __restrict__ flag,
    const float* __restrict__ wAllf, const float* __restrict__ bAllf,
    ushort* __restrict__ theta, ushort* __restrict__ phi, ushort* __restrict__ gm)
{
  int b = blockIdx.y;
  int grp = blockIdx.x >> 6, qt = blockIdx.x & 63;
  int t = threadIdx.x, lane = t & 63;
  int q = qt * 256 + t;
  int f = flag[0];
  const float* wp = wAllf + (grp << 11);

  const ushort* xb = (f ? xc : (const ushort*)x) + (size_t)b * CH * NQ + q;

  float acc[16];
  #pragma unroll
  for (int o = 0; o < 16; ++o) acc[o] = 0.f;

  for (int c0 = 0; c0 < CH; c0 += 8) {
    float xv[8];
    #pragma unroll
    for (int k = 0; k < 8; ++k) xv[k] = bf2f(xb[(size_t)(c0 + k) * NQ]);
    #pragma unroll
    for (int o = 0; o < 16; ++o) {
      #pragma unroll
      for (int k = 0; k < 8; ++k) acc[o] = fmaf(xv[k], wp[o * 128 + c0 + k], acc[o]);
    }
  }

  int bb = grp * 16;
  constexpr float L2E = 1.4426950408889634f;

  if (grp == 0) {
    union { uint4 v4[2]; ushort s[16]; } th;
    #pragma unroll
    for (int o = 0; o < 16; ++o) th.s[o] = f2bf(tanhf(acc[o] + bAllf[o]) * L2E);
    uint4* dst = (uint4*)(theta + ((size_t)b * NQ + q) * 16);
    dst[0] = th.v4[0]; dst[1] = th.v4[1];
  } else {
    float z[16];
    #pragma unroll
    for (int o = 0; o < 16; ++o) {
      float m2 = acc[o] + bAllf[bb + o];
      m2 = fmaxf(m2, __shfl_xor(m2, 1, 64));    // h-pair
      z[o] = fmaxf(m2, __shfl_xor(m2, 32, 64)); // w-pair
    }
    if ((lane & 1) == 0 && (lane & 32) == 0) {
      int hh = q & 31, ww = (q >> 5) & 31, nn = q >> 10;
      int m = nn * 256 + (ww >> 1) * 16 + (hh >> 1);
      if (grp == 1) {
        union { uint4 v4[2]; ushort s[16]; } ph;
        #pragma unroll
        for (int o = 0; o < 16; ++o) ph.s[o] = f2bf(tanhf(z[o]));
        uint4* pdst = (uint4*)(phi + ((size_t)b * NM + m) * 16);
        pdst[0] = ph.v4[0]; pdst[1] = ph.v4[1];
      } else {
        int c0 = bb - 32;
        union { uint4 v4[2]; ushort s[16]; } gv;
        #pragma unroll
        for (int o = 0; o < 16; ++o) gv.s[o] = f2bf(z[o]);
        uint4* gdst = (uint4*)(gm + ((size_t)b * NM + m) * 64 + c0);
        gdst[0] = gv.v4[0]; gdst[1] = gv.v4[1];
      }
    }
  }
}

// ---------------- softmax denominator partials ----------------
__global__ __launch_bounds__(256, 8) void k_denom(
    const ushort* __restrict__ theta, const ushort* __restrict__ phi,
    float* __restrict__ partial)
{
  int b = blockIdx.z, qs = blockIdx.y;
  int w = threadIdx.x >> 6;
  int l = threadIdx.x & 63, lr = l & 31, lh = l >> 5;
  int m0 = blockIdx.x * 128 + w * 32;

  bf16x8 pB = __builtin_bit_cast(bf16x8, *(const uint4*)(phi + ((size_t)b * NM + m0 + lr) * 16 + lh * 8));

  float s = 0.f;
  int qb = qs * 512;
  for (int qq = 0; qq < 512; qq += 32) {
    bf16x8 tA = __builtin_bit_cast(bf16x8, *(const uint4*)(theta + ((size_t)b * NQ + qb + qq + lr) * 16 + lh * 8));
    f32x16 S;
    #pragma unroll
    for (int i = 0; i < 16; ++i) S[i] = 0.f;
    S = mfma_bf16(tA, pB, S);
    #pragma unroll
    for (int r = 0; r < 16; ++r) s += exp2f(S[r]);
  }
  s += __shfl_xor(s, 32, 64);
  if (l < 32) partial[(((size_t)b * 32 + qs) << 12) + m0 + lr] = s;
}

// ---------------- dinv reduce + scale + PV B-frag pack ----------------
// Block: (b, 32-m chunk). Emits gsF[b][ms][ct][lane] j-th bf16 =
// (g[ms*16+(lane>>5)*8+j][ct*32+(lane&31)]) / denom[m]  -- R2-verified layout,
// so k_attn's 4 g-loads per iter are lane-contiguous (1 KB each).
__global__ __launch_bounds__(256) void k_gsf(
    const float* __restrict__ partial, const ushort* __restrict__ gm,
    uint4* __restrict__ gsF)
{
  int b = blockIdx.y, mb = blockIdx.x;   // 128 chunks of 32 m
  int t = threadIdx.x;
  int mbase = mb * 32;

  __shared__ float dinv_sh[32];
  __shared__ float tile[32][65];

  if (t < 32) {
    int m = mbase + t;
    float s = 0.f;
    #pragma unroll
    for (int p = 0; p < 32; ++p) s += partial[(((size_t)b * 32 + p) << 12) + m];
    dinv_sh[t] = 1.f / s;
  }
  __syncthreads();

  {
    int m_loc = t >> 3, c = (t & 7) * 8;
    union { uint4 v4; ushort s[8]; } v;
    v.v4 = *(const uint4*)(gm + ((size_t)b * NM + mbase + m_loc) * 64 + c);
    float dv = dinv_sh[m_loc];
    #pragma unroll
    for (int j = 0; j < 8; ++j) tile[m_loc][c + j] = bf2f(v.s[j]) * dv;
  }
  __syncthreads();

  int ms_loc = t >> 7, ct = (t >> 6) & 1, lane = t & 63;
  int col = ct * 32 + (lane & 31);
  int rbase = ms_loc * 16 + (lane >> 5) * 8;
  union { uint4 v4; ushort s[8]; } o;
  #pragma unroll
  for (int j = 0; j < 8; ++j) o.s[j] = f2bf(tile[rbase + j][col]);
  int ms = (mbase >> 4) + ms_loc;
  gsF[(((size_t)b * 256 + ms) * 2 + ct) * 64 + lane] = o.v4;
}

// ---------------- fused attention + output ----------------
// 1024 threads = 16 waves = (qh 2) x (mq 8); 64 q/block; 16 m-iters/wave.
// g-frag loads now COALESCED via gsF. 1-deep prefetch pinned with
// sched_barrier(0) so the compiler can't sink the loads back to their uses.
__global__ __launch_bounds__(1024, 4) void k_attn(
    const ushort* __restrict__ theta, const ushort* __restrict__ phi,
    const uint4* __restrict__ gsF, const uint4* __restrict__ wF,
    const float* __restrict__ bAllf, const void* __restrict__ x,
    const void* __restrict__ gamma, const int* __restrict__ flag,
    void* __restrict__ out_base)
{
  int b = blockIdx.y;
  int q0 = blockIdx.x * 64;
  int t = threadIdx.x;
  int w = t >> 6, l = t & 63, lr = l & 31, lh = l >> 5;
  int mq = w & 7, qh = w >> 3;

  __shared__ float agPart[8][32][65];
  __shared__ __align__(16) ushort agF[32][80];

  int qw = q0 + qh * 32;
  bf16x8 tB = __builtin_bit_cast(bf16x8, *(const uint4*)(theta + ((size_t)b * NQ + qw + lr) * 16 + lh * 8));

  const ushort* phb = phi + ((size_t)b * NM + lr) * 16 + lh * 8;
  const uint4* gF = gsF + (size_t)b * 256 * 128;   // per-ms stride = 128 uint4

  f32x16 acc0, acc1;
  #pragma unroll
  for (int i = 0; i < 16; ++i) { acc0[i] = 0.f; acc1[i] = 0.f; }

  int m0 = mq * 32;
  int ms0 = m0 >> 4;
  bf16x8 pA = __builtin_bit_cast(bf16x8, *(const uint4*)(phb + (size_t)m0 * 16));
  uint4 g00 = gF[ms0 * 128 + l];
  uint4 g01 = gF[ms0 * 128 + 64 + l];
  uint4 g10 = gF[ms0 * 128 + 128 + l];
  uint4 g11 = gF[ms0 * 128 + 192 + l];

  for (int it = 0; it < 16; ++it) {
    f32x16 S;
    #pragma unroll
    for (int i = 0; i < 16; ++i) S[i] = 0.f;
    S = mfma_bf16(pA, tB, S);   // S^T[m][q] (theta pre-scaled by log2e)

    // issue next-iter loads (wrap on last iter; values unused)
    int mn = mq * 32 + ((it + 1) & 15) * 256;
    int msn = mn >> 4;
    bf16x8 pAn = __builtin_bit_cast(bf16x8, *(const uint4*)(phb + (size_t)mn * 16));
    uint4 n00 = gF[msn * 128 + l];
    uint4 n01 = gF[msn * 128 + 64 + l];
    uint4 n10 = gF[msn * 128 + 128 + l];
    uint4 n11 = gF[msn * 128 + 192 + l];
    __builtin_amdgcn_sched_barrier(0);   // pin: loads issued before the VALU block

    #pragma unroll
    for (int r = 0; r < 16; ++r) S[r] = exp2f(S[r]);   // unnormalized P

    uint u0, u1, u2, u3, u4, u5, u6, u7;
    asm("v_cvt_pk_bf16_f32 %0, %1, %2" : "=v"(u0) : "v"(S[0]),  "v"(S[1]));
    asm("v_cvt_pk_bf16_f32 %0, %1, %2" : "=v"(u1) : "v"(S[2]),  "v"(S[3]));
    asm("v_cvt_pk_bf16_f32 %0, %1, %2" : "=v"(u2) : "v"(S[4]),  "v"(S[5]));
    asm("v_cvt_pk_bf16_f32 %0, %1, %2" : "=v"(u3) : "v"(S[6]),  "v"(S[7]));
    asm("v_cvt_pk_bf16_f32 %0, %1, %2" : "=v"(u4) : "v"(S[8]),  "v"(S[9]));
    asm("v_cvt_pk_bf16_f32 %0, %1, %2" : "=v"(u5) : "v"(S[10]), "v"(S[11]));
    asm("v_cvt_pk_bf16_f32 %0, %1, %2" : "=v"(u6) : "v"(S[12]), "v"(S[13]));
    asm("v_cvt_pk_bf16_f32 %0, %1, %2" : "=v"(u7) : "v"(S[14]), "v"(S[15]));

    asm("v_permlane32_swap_b32 %0, %1" : "+v"(u0), "+v"(u2));
    asm("v_permlane32_swap_b32 %0, %1" : "+v"(u1), "+v"(u3));
    asm("v_permlane32_swap_b32 %0, %1" : "+v"(u4), "+v"(u6));
    asm("v_permlane32_swap_b32 %0, %1" : "+v"(u5), "+v"(u7));

    uint4 fa0 = make_uint4(u0, u1, u2, u3);
    uint4 fa1 = make_uint4(u4, u5, u6, u7);

    acc0 = mfma_bf16(__builtin_bit_cast(bf16x8, fa0), __builtin_bit_cast(bf16x8, g00), acc0);
    acc1 = mfma_bf16(__builtin_bit_cast(bf16x8, fa0), __builtin_bit_cast(bf16x8, g01), acc1);
    acc0 = mfma_bf16(__builtin_bit_cast(bf16x8, fa1), __builtin_bit_cast(bf16x8, g10), acc0);
    acc1 = mfma_bf16(__builtin_bit_cast(bf16x8, fa1), __builtin_bit_cast(bf16x8, g11), acc1);

    pA = pAn; g00 = n00; g01 = n01; g10 = n10; g11 = n11;
  }

  int mode = flag[0];
  float ga = ldany(gamma, 0, mode);
  float alpha = 1.f / (1.f + __expf(-ga));

  #pragma unroll
  for (int h = 0; h < 2; ++h) {
    __syncthreads();
    if (qh == h) {
      #pragma unroll
      for (int r = 0; r < 16; ++r) {
        int qq = (r & 3) + 8 * (r >> 2) + 4 * lh;
        agPart[mq][qq][lr]      = acc0[r];
        agPart[mq][qq][32 + lr] = acc1[r];
      }
    }
    __syncthreads();
    if (t < 256) {
      int w2 = t >> 6, l2 = t & 63, lr2 = l2 & 31, lh2 = l2 >> 5;
      #pragma unroll
      for (int jj = 0; jj < 8; ++jj) {
        int c = w2 * 16 + lh2 * 8 + jj;
        float vsum = 0.f;
        #pragma unroll
        for (int p = 0; p < 8; ++p) vsum += agPart[p][lr2][c];
        agF[lr2][c] = f2bf(vsum);
      }
    }
    __syncthreads();
    if (qh == h && mq < 4) {
      f32x16 oacc;
      #pragma unroll
      for (int i = 0; i < 16; ++i) oacc[i] = 0.f;
      #pragma unroll
      for (int ks = 0; ks < 4; ++ks) {
        bf16x8 aw = __builtin_bit_cast(bf16x8, wF[(mq * 4 + ks) * 64 + l]);
        bf16x8 bg = __builtin_bit_cast(bf16x8, *(const uint4*)&agF[lr][ks * 16 + lh * 8]);
        oacc = mfma_bf16(aw, bg, oacc);
      }
      if (mode) {
        float* o0 = (float*)out_base;
        float* o1 = o0 + NX;
        const float* xf = (const float*)x;
        #pragma unroll
        for (int r = 0; r < 16; ++r) {
          int o = mq * 32 + (r & 3) + 8 * (r >> 2) + 4 * lh;
          size_t oi = ((size_t)b * CH + o) * NQ + q0 + h * 32 + lr;
          float ag = oacc[r] + bAllf[96 + o];
          o0[oi] = (1.f - alpha) * xf[oi] + alpha * ag;
          o1[oi] = ag;
        }
      } else {
        ushort* o0 = (ushort*)out_base;
        ushort* o1 = o0 + NX;
        const ushort* xu = (const ushort*)x;
        #pragma unroll
        for (int r = 0; r < 16; ++r) {
          int o = mq * 32 + (r & 3) + 8 * (r >> 2) + 4 * lh;
          size_t oi = ((size_t)b * CH + o) * NQ + q0 + h * 32 + lr;
          float ag = oacc[r] + bAllf[96 + o];
          o0[oi] = f2bf((1.f - alpha) * bf2f(xu[oi]) + alpha * ag);
          o1[oi] = f2bf(ag);
        }
      }
    }
  }
}

extern "C" void kernel_launch(void* const* d_in, const int* in_sizes, int n_in,
                              void* d_out, int out_size, void* d_ws, size_t ws_size,
                              hipStream_t stream) {
  const void* x    = d_in[0];
  const void* wT   = d_in[1];
  const void* bT   = d_in[2];
  const void* wP   = d_in[3];
  const void* bP   = d_in[4];
  const void* wG   = d_in[5];
  const void* bG   = d_in[6];
  const void* wAG  = d_in[7];
  const void* bAG  = d_in[8];
  const void* gmm  = d_in[9];

  char* ws = (char*)d_ws;
  ushort* theta  = (ushort*)(ws + 0);          // 1 MB
  ushort* phi    = (ushort*)(ws + 1048576);    // 256 KB
  ushort* gm     = (ushort*)(ws + 1310720);    // 1 MB  [b][m][64] bf16
  float*  part   = (float*) (ws + 2359296);    // 1 MB
  uint4*  gsF    = (uint4*) (ws + 3407872);    // 1 MB  pre-swizzled PV B-frags
  uint4*  wF     = (uint4*) (ws + 4456448);    // 16 KB
  float*  wAllf  = (float*) (ws + 4472832);    // 48 KB
  float*  bAllf  = (float*) (ws + 4521984);    // 1 KB
  int*    flag   = (int*)   (ws + 4523008);    // 4 B
  ushort* xc     = (ushort*)(ws + 4523264);    // 8 MB canonical bf16 x

  k_sniff<<<dim3(1), dim3(64), 0, stream>>>(x, flag);
  k_convert<<<dim3(2048), dim3(256), 0, stream>>>(x, flag, xc);
  k_prep<<<dim3(5), dim3(256), 0, stream>>>(wT, bT, wP, bP, wG, bG, wAG, bAG, flag, wAllf, bAllf, wF);
  k_proj<<<dim3(384, 2), dim3(256), 0, stream>>>(x, xc, flag, wAllf, bAllf, theta, phi, gm);
  k_denom<<<dim3(32, 32, 2), dim3(256), 0, stream>>>(theta, phi, part);
  k_gsf<<<dim3(128, 2), dim3(256), 0, stream>>>(part, gm, gsF);
  k_attn<<<dim3(256, 2), dim3(1024), 0, stream>>>(theta, phi, gsF, wF, bAllf, x, gmm, flag, d_out);
}